// Round 2
// baseline (501.090 us; speedup 1.0000x reference)
//
#include <hip/hip_runtime.h>
#include <hip/hip_bf16.h>

typedef __attribute__((ext_vector_type(8))) short short8;
typedef __attribute__((ext_vector_type(4))) float floatx4;

#define C_DIM 256
#define NCE_T_INV 14.285714285714286f

// ---------------------------------------------------------------------------
// Kernel 1: gather downsampled labels.
// ---------------------------------------------------------------------------
__global__ void labels_kernel(const int* __restrict__ seg,
                              const int* __restrict__ coords,
                              const int* __restrict__ crw,
                              const int* __restrict__ crh,
                              const int* __restrict__ crd,
                              int* __restrict__ lab, int N, int H, int W, int D) {
    int p = blockIdx.x * blockDim.x + threadIdx.x;
    if (p >= N) return;
    int c0 = coords[3 * p + 0];
    int c1 = coords[3 * p + 1];
    int c2 = coords[3 * p + 2];
    int i0 = (c0 * H) / crw[0];
    int i1 = (c1 * W) / crh[0];
    int i2 = (c2 * D) / crd[0];
    lab[p] = seg[(i0 * W + i1) * D + i2];
}

// ---------------------------------------------------------------------------
// Kernel 2: L2-normalize rows of f (M x 256 fp32) -> bf16 bits in g.
// One wave per row.
// ---------------------------------------------------------------------------
__global__ void norm_kernel(const float* __restrict__ f,
                            unsigned short* __restrict__ g) {
    int row = blockIdx.x;
    int lane = threadIdx.x;  // 0..63
    const float4 v = ((const float4*)(f + (size_t)row * C_DIM))[lane];
    float ss = v.x * v.x + v.y * v.y + v.z * v.z + v.w * v.w;
#pragma unroll
    for (int off = 32; off; off >>= 1) ss += __shfl_xor(ss, off, 64);
    float inv = 1.0f / sqrtf(ss);

    ushort4 o;
    __hip_bfloat16 b0 = __float2bfloat16(v.x * inv);
    __hip_bfloat16 b1 = __float2bfloat16(v.y * inv);
    __hip_bfloat16 b2 = __float2bfloat16(v.z * inv);
    __hip_bfloat16 b3 = __float2bfloat16(v.w * inv);
    o.x = __builtin_bit_cast(unsigned short, b0);
    o.y = __builtin_bit_cast(unsigned short, b1);
    o.z = __builtin_bit_cast(unsigned short, b2);
    o.w = __builtin_bit_cast(unsigned short, b3);
    ((ushort4*)g)[(size_t)row * (C_DIM / 4) + lane] = o;
}

// ---------------------------------------------------------------------------
// Kernel 3: symmetric fused Gram-tile kernel. Tiles with tn >= tm only.
// LDS: two K-panels per array, [arr][panel][row 128][32 shorts] — row stride
// 16 dwords (== 16 mod 32) = m97-style conflict-light layout, contiguous for
// global_load_lds width-16 DMA staging. Epilogue: per-row partials via LDS
// fire-and-forget float adds, then plain (atomic-free) stores into a unique
// slot of part[64][M][3]: A-side -> slot tn (rows of tm), B-side -> slot tm
// (rows of tn). Each (slot,row) written exactly once across the grid.
// ---------------------------------------------------------------------------
struct Smem {
    union {
        unsigned short tiles[2][2][128][32];  // 32 KB
        float red[2][128][3];                 // 3 KB, reused after K-loop
    };
};

__global__ __launch_bounds__(256, 4) void
gram_kernel(const unsigned short* __restrict__ G,
            const int* __restrict__ lab,
            float* __restrict__ part,
            int M, int labmask) {
    const int tn = blockIdx.x;
    const int tm = blockIdx.y;
    if (tn < tm) return;

    __shared__ Smem sm;
    const int tid = threadIdx.x;
    const int lane = tid & 63;
    const int wave = tid >> 6;
    const int waveM = wave >> 1;
    const int waveN = wave & 1;
    const int cc = lane & 15;
    const int cq = lane >> 4;
    const int rowA0 = tm * 128;
    const int rowB0 = tn * 128;

    floatx4 acc[4][4] = {};
    unsigned short* tflat = &sm.tiles[0][0][0][0];

    for (int kk = 0; kk < C_DIM; kk += 64) {
        // ---- stage via global->LDS DMA (width 16) ----
#pragma unroll
        for (int arr = 0; arr < 2; ++arr) {
            const int row0 = arr ? rowB0 : rowA0;
#pragma unroll
            for (int j = 0; j < 4; ++j) {
                const int u = j * 256 + tid;          // 16B-unit index, 0..1023
                const int s = u >> 9;                 // K-panel
                const int row = (u >> 2) & 127;
                const int cb = u & 3;                 // 16B block in 64B panel-row
                const unsigned short* gp =
                    G + (size_t)(row0 + row) * C_DIM + kk + s * 32 + cb * 8;
                // wave-uniform LDS base; HW adds lane*16
                unsigned short* lp = tflat + ((size_t)arr * 1024 + (u & ~63)) * 8;
                __builtin_amdgcn_global_load_lds(
                    (const __attribute__((address_space(1))) void*)gp,
                    (__attribute__((address_space(3))) void*)lp, 16, 0, 0);
            }
        }
        __syncthreads();

        // ---- MFMA over the two 32-wide K panels ----
#pragma unroll
        for (int s = 0; s < 2; ++s) {
            short8 af[4], bf[4];
#pragma unroll
            for (int mi = 0; mi < 4; ++mi)
                af[mi] = *(const short8*)&sm.tiles[0][s][waveM * 64 + mi * 16 + cc][cq * 8];
#pragma unroll
            for (int ni = 0; ni < 4; ++ni)
                bf[ni] = *(const short8*)&sm.tiles[1][s][waveN * 64 + ni * 16 + cc][cq * 8];
#pragma unroll
            for (int mi = 0; mi < 4; ++mi)
#pragma unroll
                for (int ni = 0; ni < 4; ++ni)
                    acc[mi][ni] = __builtin_amdgcn_mfma_f32_16x16x32_bf16(
                        af[mi], bf[ni], acc[mi][ni], 0, 0, 0);
        }
        __syncthreads();
    }

    // ---- epilogue ----
    float* redf = &sm.red[0][0][0];
    for (int v = tid; v < 768; v += 256) redf[v] = 0.0f;
    __syncthreads();

    const bool diagTile = (tm == tn);

    int col_lab[4];
#pragma unroll
    for (int ni = 0; ni < 4; ++ni)
        col_lab[ni] = lab[(rowB0 + waveN * 64 + ni * 16 + cc) & labmask];

    float bse[4] = {}, bnu[4] = {}, bct[4] = {};

#pragma unroll
    for (int mi = 0; mi < 4; ++mi) {
#pragma unroll
        for (int r = 0; r < 4; ++r) {
            const int lrow = waveM * 64 + mi * 16 + cq * 4 + r;
            const int grow = rowA0 + lrow;
            const int rl = lab[grow & labmask];
            float se = 0.0f, nu = 0.0f, ct = 0.0f;
#pragma unroll
            for (int ni = 0; ni < 4; ++ni) {
                const int gcol = rowB0 + waveN * 64 + ni * 16 + cc;
                const float ls = (acc[mi][ni][r] - 1.0f) * NCE_T_INV;
                const bool valid = (gcol != grow);
                const float e = valid ? __expf(ls) : 0.0f;
                const bool pos = valid && (col_lab[ni] == rl);
                const float nuv = pos ? ls : 0.0f;
                const float p = pos ? 1.0f : 0.0f;
                se += e; nu += nuv; ct += p;
                bse[ni] += e; bnu[ni] += nuv; bct[ni] += p;
            }
            unsafeAtomicAdd(&sm.red[0][lrow][0], se);
            unsafeAtomicAdd(&sm.red[0][lrow][1], nu);
            unsafeAtomicAdd(&sm.red[0][lrow][2], ct);
        }
    }
    if (!diagTile) {
#pragma unroll
        for (int ni = 0; ni < 4; ++ni) {
            const int lcol = waveN * 64 + ni * 16 + cc;
            unsafeAtomicAdd(&sm.red[1][lcol][0], bse[ni]);
            unsafeAtomicAdd(&sm.red[1][lcol][1], bnu[ni]);
            unsafeAtomicAdd(&sm.red[1][lcol][2], bct[ni]);
        }
    }
    __syncthreads();

    // A-side partials -> slot tn, rows of tile tm
    for (int v = tid; v < 384; v += 256) {
        const int r = v / 3, c = v % 3;
        part[((size_t)tn * M + rowA0 + r) * 3 + c] = sm.red[0][r][c];
    }
    // B-side partials -> slot tm, rows of tile tn
    if (!diagTile) {
        for (int v = tid; v < 384; v += 256) {
            const int r = v / 3, c = v % 3;
            part[((size_t)tm * M + rowB0 + r) * 3 + c] = sm.red[1][r][c];
        }
    }
}

// ---------------------------------------------------------------------------
// Kernel 4: per-row term = nu/ct - log(se), reducing over the 64 slots.
// ---------------------------------------------------------------------------
__global__ void rowterm_kernel(const float* __restrict__ part,
                               float* __restrict__ terms, int M, int nslots) {
    const int row = blockIdx.x * 256 + threadIdx.x;
    if (row >= M) return;
    float se = 0.0f, nu = 0.0f, ct = 0.0f;
    for (int s = 0; s < nslots; ++s) {
        const float* p = part + ((size_t)s * M + row) * 3;
        se += p[0];
        nu += p[1];
        ct += p[2];
    }
    terms[row] = nu / ct - logf(se);
}

// ---------------------------------------------------------------------------
// Kernel 5: final mean.
// ---------------------------------------------------------------------------
__global__ void reduce_kernel(const float* __restrict__ terms,
                              float* __restrict__ out, int M) {
    __shared__ float red[256];
    float s = 0.0f;
    for (int i = threadIdx.x; i < M; i += 256) s += terms[i];
    red[threadIdx.x] = s;
    __syncthreads();
    for (int k = 128; k; k >>= 1) {
        if (threadIdx.x < k) red[threadIdx.x] += red[threadIdx.x + k];
        __syncthreads();
    }
    if (threadIdx.x == 0) out[0] = -red[0] / (float)M;
}

extern "C" void kernel_launch(void* const* d_in, const int* in_sizes, int n_in,
                              void* d_out, int out_size, void* d_ws, size_t ws_size,
                              hipStream_t stream) {
    const float* features = (const float*)d_in[0];
    const int* labels_seg = (const int*)d_in[1];
    const int* labels_coords = (const int*)d_in[2];
    const int* crw = (const int*)d_in[3];
    const int* crh = (const int*)d_in[4];
    const int* crd = (const int*)d_in[5];
    float* out = (float*)d_out;

    const int N = in_sizes[2] / 3;        // 4096 patches
    const int M = in_sizes[0] / C_DIM;    // 8192 rows
    const int H = 128, W = 128, D = 128;
    const int ntiles = M / 128;           // 64

    // workspace layout
    char* ws = (char*)d_ws;
    unsigned short* g = (unsigned short*)ws;                       // M*256 bf16 (4 MB)
    char* p1 = ws + (size_t)M * C_DIM * 2;
    int* lab = (int*)p1;                                           // N ints
    char* p2 = p1 + (size_t)N * 4;
    float* part = (float*)p2;                                      // ntiles*M*3 f32 (6.3 MB)
    char* p3 = p2 + (size_t)ntiles * M * 3 * 4;
    float* terms = (float*)p3;                                     // M f32

    labels_kernel<<<(N + 255) / 256, 256, 0, stream>>>(
        labels_seg, labels_coords, crw, crh, crd, lab, N, H, W, D);

    norm_kernel<<<M, 64, 0, stream>>>(features, g);

    dim3 grid(ntiles, ntiles);
    gram_kernel<<<grid, 256, 0, stream>>>(g, lab, part, M, N - 1);

    rowterm_kernel<<<(M + 255) / 256, 256, 0, stream>>>(part, terms, M, ntiles);

    reduce_kernel<<<1, 256, 0, stream>>>(terms, out, M);
}

// Round 3
// 238.581 us; speedup vs baseline: 2.1003x; 2.1003x over previous
//
#include <hip/hip_runtime.h>
#include <hip/hip_bf16.h>

typedef __attribute__((ext_vector_type(8))) short short8;
typedef __attribute__((ext_vector_type(4))) float floatx4;

#define C_DIM 256
#define NCE_T_INV 14.285714285714286f

// ---------------------------------------------------------------------------
// Kernel 1: gather downsampled labels.
// ---------------------------------------------------------------------------
__global__ void labels_kernel(const int* __restrict__ seg,
                              const int* __restrict__ coords,
                              const int* __restrict__ crw,
                              const int* __restrict__ crh,
                              const int* __restrict__ crd,
                              int* __restrict__ lab, int N, int H, int W, int D) {
    int p = blockIdx.x * blockDim.x + threadIdx.x;
    if (p >= N) return;
    int c0 = coords[3 * p + 0];
    int c1 = coords[3 * p + 1];
    int c2 = coords[3 * p + 2];
    int i0 = (c0 * H) / crw[0];
    int i1 = (c1 * W) / crh[0];
    int i2 = (c2 * D) / crd[0];
    lab[p] = seg[(i0 * W + i1) * D + i2];
}

// ---------------------------------------------------------------------------
// Kernel 2: L2-normalize rows of f (M x 256 fp32) -> bf16 bits in g.
// One wave per row, 4 rows per block.
// ---------------------------------------------------------------------------
__global__ void norm_kernel(const float* __restrict__ f,
                            unsigned short* __restrict__ g) {
    int row = blockIdx.x * 4 + (threadIdx.x >> 6);
    int lane = threadIdx.x & 63;
    const float4 v = ((const float4*)(f + (size_t)row * C_DIM))[lane];
    float ss = v.x * v.x + v.y * v.y + v.z * v.z + v.w * v.w;
#pragma unroll
    for (int off = 32; off; off >>= 1) ss += __shfl_xor(ss, off, 64);
    float inv = 1.0f / sqrtf(ss);

    ushort4 o;
    __hip_bfloat16 b0 = __float2bfloat16(v.x * inv);
    __hip_bfloat16 b1 = __float2bfloat16(v.y * inv);
    __hip_bfloat16 b2 = __float2bfloat16(v.z * inv);
    __hip_bfloat16 b3 = __float2bfloat16(v.w * inv);
    o.x = __builtin_bit_cast(unsigned short, b0);
    o.y = __builtin_bit_cast(unsigned short, b1);
    o.z = __builtin_bit_cast(unsigned short, b2);
    o.w = __builtin_bit_cast(unsigned short, b3);
    ((ushort4*)g)[(size_t)row * (C_DIM / 4) + lane] = o;
}

// ---------------------------------------------------------------------------
// Kernel 3: zero the per-row accumulators.
// ---------------------------------------------------------------------------
__global__ void zero_kernel(float* __restrict__ p, int n) {
    int i = blockIdx.x * blockDim.x + threadIdx.x;
    if (i < n) p[i] = 0.0f;
}

// ---------------------------------------------------------------------------
// Kernel 4: symmetric Gram-tile kernel, round-1 proven structure.
// 1D triangular grid: block b -> (tm, tn) with tn >= tm; 2080 blocks for 64
// tiles. VGPR-staged LDS tiles, BK=64, pad to 72 shorts (stride 36 dwords
// == 4 mod 32 -> free 2-way ds_read_b128 pattern, measured 4.2e6 conflicts
// in round 1). 36.9 KB LDS -> 4 blocks/CU. Epilogue: in-register + shuffle
// reductions; A-side row sums via cc-butterfly (3 atomics / 16 lanes);
// off-diag blocks also emit B-side column sums via cq-butterfly
// (12 atomics / wave). Every sim element computed once, contributes twice.
// ---------------------------------------------------------------------------
__global__ __launch_bounds__(256, 4) void
gram_kernel(const unsigned short* __restrict__ G,
            const int* __restrict__ lab,
            float* __restrict__ rs_exp,
            float* __restrict__ rs_num,
            float* __restrict__ rs_cnt,
            int labmask, int nt) {
    // ---- decode triangular block index (wave-uniform) ----
    const int b = blockIdx.x;
    float fnt = (float)nt;
    float disc = (2.0f * fnt + 1.0f) * (2.0f * fnt + 1.0f) - 8.0f * (float)b;
    int tm = (int)((2.0f * fnt + 1.0f - sqrtf(disc)) * 0.5f);
    if (tm < 0) tm = 0;
    if (tm > nt - 1) tm = nt - 1;
    while (tm > 0 && b < tm * nt - tm * (tm - 1) / 2) --tm;
    while (b >= (tm + 1) * nt - (tm + 1) * tm / 2) ++tm;
    const int tn = tm + (b - (tm * nt - tm * (tm - 1) / 2));

    __shared__ unsigned short As[128][72];
    __shared__ unsigned short Bs[128][72];

    const int tid = threadIdx.x;
    const int lane = tid & 63;
    const int wave = tid >> 6;
    const int waveM = wave >> 1;
    const int waveN = wave & 1;
    const int cc = lane & 15;
    const int cq = lane >> 4;
    const int rowA0 = tm * 128;
    const int rowB0 = tn * 128;
    const bool diagTile = (tm == tn);

    floatx4 acc[4][4] = {};

    for (int kk = 0; kk < C_DIM; kk += 64) {
        // ---- stage A and B tiles (128 x 64 bf16 each) via VGPRs ----
#pragma unroll
        for (int t = 0; t < 8; ++t) {
            const int vi = t * 256 + tid;       // 0..2047
            const int row = (vi >> 3) & 127;
            const int cv = vi & 7;              // 8-elem chunk
            const uint4 val =
                *(const uint4*)&G[(size_t)((t < 4 ? rowA0 : rowB0) + row) * C_DIM + kk + cv * 8];
            if (t < 4) *(uint4*)&As[row][cv * 8] = val;
            else       *(uint4*)&Bs[row][cv * 8] = val;
        }
        __syncthreads();

        // ---- MFMA over the two 32-wide K panels ----
#pragma unroll
        for (int ks = 0; ks < 64; ks += 32) {
            short8 af[4], bf[4];
#pragma unroll
            for (int mi = 0; mi < 4; ++mi)
                af[mi] = *(const short8*)&As[waveM * 64 + mi * 16 + cc][ks + cq * 8];
#pragma unroll
            for (int ni = 0; ni < 4; ++ni)
                bf[ni] = *(const short8*)&Bs[waveN * 64 + ni * 16 + cc][ks + cq * 8];
#pragma unroll
            for (int mi = 0; mi < 4; ++mi)
#pragma unroll
                for (int ni = 0; ni < 4; ++ni)
                    acc[mi][ni] = __builtin_amdgcn_mfma_f32_16x16x32_bf16(
                        af[mi], bf[ni], acc[mi][ni], 0, 0, 0);
        }
        __syncthreads();
    }

    // ---- epilogue ----
    int col_lab[4];
#pragma unroll
    for (int ni = 0; ni < 4; ++ni)
        col_lab[ni] = lab[(rowB0 + waveN * 64 + ni * 16 + cc) & labmask];

    float bse[4] = {}, bnu[4] = {}, bct[4] = {};

#pragma unroll
    for (int mi = 0; mi < 4; ++mi) {
#pragma unroll
        for (int r = 0; r < 4; ++r) {
            const int grow = rowA0 + waveM * 64 + mi * 16 + cq * 4 + r;
            const int rl = lab[grow & labmask];
            float se = 0.0f, nu = 0.0f, ct = 0.0f;
#pragma unroll
            for (int ni = 0; ni < 4; ++ni) {
                const int gcol = rowB0 + waveN * 64 + ni * 16 + cc;
                const float ls = (acc[mi][ni][r] - 1.0f) * NCE_T_INV;
                const bool valid = (gcol != grow);
                const float e = valid ? __expf(ls) : 0.0f;
                const bool pos = valid && (col_lab[ni] == rl);
                const float nuv = pos ? ls : 0.0f;
                const float p = pos ? 1.0f : 0.0f;
                se += e; nu += nuv; ct += p;
                bse[ni] += e; bnu[ni] += nuv; bct[ni] += p;
            }
            // reduce across the 16 cc lanes (rows)
#pragma unroll
            for (int off = 1; off < 16; off <<= 1) {
                se += __shfl_xor(se, off, 64);
                nu += __shfl_xor(nu, off, 64);
                ct += __shfl_xor(ct, off, 64);
            }
            if (cc == 0) {
                atomicAdd(&rs_exp[grow], se);
                atomicAdd(&rs_num[grow], nu);
                atomicAdd(&rs_cnt[grow], ct);
            }
        }
    }

    // ---- mirrored (column-side) contributions for off-diagonal tiles ----
    if (!diagTile) {
#pragma unroll
        for (int ni = 0; ni < 4; ++ni) {
            float se = bse[ni], nu = bnu[ni], ct = bct[ni];
            // reduce across the 4 cq lanes (rows of this wave's strip)
            se += __shfl_xor(se, 16, 64); nu += __shfl_xor(nu, 16, 64); ct += __shfl_xor(ct, 16, 64);
            se += __shfl_xor(se, 32, 64); nu += __shfl_xor(nu, 32, 64); ct += __shfl_xor(ct, 32, 64);
            if (cq == 0) {
                const int gcol = rowB0 + waveN * 64 + ni * 16 + cc;
                atomicAdd(&rs_exp[gcol], se);
                atomicAdd(&rs_num[gcol], nu);
                atomicAdd(&rs_cnt[gcol], ct);
            }
        }
    }
}

// ---------------------------------------------------------------------------
// Kernel 5: finalize. loss = -mean_i( num_i/cnt_i - log(exp_i) )
// ---------------------------------------------------------------------------
__global__ void finalize_kernel(const float* __restrict__ rs_exp,
                                const float* __restrict__ rs_num,
                                const float* __restrict__ rs_cnt,
                                float* __restrict__ out, int M) {
    __shared__ float red[256];
    float s = 0.0f;
    for (int i = threadIdx.x; i < M; i += 256)
        s += rs_num[i] / rs_cnt[i] - logf(rs_exp[i]);
    red[threadIdx.x] = s;
    __syncthreads();
    for (int k = 128; k; k >>= 1) {
        if (threadIdx.x < k) red[threadIdx.x] += red[threadIdx.x + k];
        __syncthreads();
    }
    if (threadIdx.x == 0) out[0] = -red[0] / (float)M;
}

extern "C" void kernel_launch(void* const* d_in, const int* in_sizes, int n_in,
                              void* d_out, int out_size, void* d_ws, size_t ws_size,
                              hipStream_t stream) {
    const float* features = (const float*)d_in[0];
    const int* labels_seg = (const int*)d_in[1];
    const int* labels_coords = (const int*)d_in[2];
    const int* crw = (const int*)d_in[3];
    const int* crh = (const int*)d_in[4];
    const int* crd = (const int*)d_in[5];
    float* out = (float*)d_out;

    const int N = in_sizes[2] / 3;        // 4096 patches
    const int M = in_sizes[0] / C_DIM;    // 8192 rows
    const int H = 128, W = 128, D = 128;
    const int nt = M / 128;               // 64 tiles
    const int nblocks = nt * (nt + 1) / 2;  // 2080

    // workspace layout
    char* ws = (char*)d_ws;
    unsigned short* g = (unsigned short*)ws;                       // M*256 bf16 (4 MB)
    char* p1 = ws + (size_t)M * C_DIM * 2;
    int* lab = (int*)p1;                                           // N ints
    char* p2 = p1 + (size_t)N * 4;
    float* rs = (float*)p2;                                        // 3*M f32
    float* rs_exp = rs;
    float* rs_num = rs + M;
    float* rs_cnt = rs + 2 * M;

    labels_kernel<<<(N + 255) / 256, 256, 0, stream>>>(
        labels_seg, labels_coords, crw, crh, crd, lab, N, H, W, D);

    norm_kernel<<<M / 4, 256, 0, stream>>>(features, g);

    zero_kernel<<<(3 * M + 255) / 256, 256, 0, stream>>>(rs, 3 * M);

    gram_kernel<<<nblocks, 256, 0, stream>>>(g, lab, rs_exp, rs_num, rs_cnt,
                                             N - 1, nt);

    finalize_kernel<<<1, 256, 0, stream>>>(rs_exp, rs_num, rs_cnt, out, M);
}